// Round 11
// baseline (319.237 us; speedup 1.0000x reference)
//
#include <hip/hip_runtime.h>
#include <hip/hip_fp16.h>
#include <cstdint>

#define TABLE_MASK 0x3FFFFFu   // 2^22 - 1
#define P2 2654435761u
#define P3 805459861u

#define XD 128                  // exdx x-extent (record x = ix in [0,127])
#define YD 132                  // cy in [1,131]
#define ZD 132                  // cz in [1,131]
#define RECU 12                 // 12 uints = 48 B per cell: Ex(6 half2) + Dx(6 half2)
#define NBT 4096                // 16^3 tiles of 8^3 cells
#define NREC 968                // 8 x 11 x 11 records per tile
#define BUILD_BLKS (131 * 66)   // 8646

__device__ __forceinline__ float sigmoidf_(float x) { return 1.0f / (1.0f + expf(-x)); }

__device__ __forceinline__ uint32_t f2h2(float a, float b) {
    __half2 h = __floats2half2_rn(a, b);
    return *reinterpret_cast<uint32_t*>(&h);
}
__device__ __forceinline__ __half2 u2h2(uint32_t u) {
    return *reinterpret_cast<__half2*>(&u);
}

// ---------- sort key: 8^3-cell tile id (tz*256 + ty*16 + tx) ----------
__device__ __forceinline__ int bin_tile(float px, float py, float pz)
{
    float x = ((px + 10.0f) / 20.0f) * 128.0f;
    float y = ((py + 10.0f) / 20.0f) * 128.0f;
    float z = ((pz + 10.0f) / 20.0f) * 128.0f;
    int ix = min(max((int)floorf(x), 0), 127);
    int iy = min(max((int)floorf(y), 0), 127);
    int iz = min(max((int)floorf(z), 0), 127);
    return ((iz >> 3) << 8) | ((iy >> 3) << 4) | (ix >> 3);
}

// ---------- fused prepass: build exdx volume + histogram ----------
__global__ __launch_bounds__(256)
void build_hist_kernel(const float4* __restrict__ gauss,
                       const float4* __restrict__ vmf,
                       uint32_t* __restrict__ exdx,
                       const float* __restrict__ pos,
                       uint32_t* __restrict__ hist, int n)
{
    if (blockIdx.x >= BUILD_BLKS) {
        int p = (blockIdx.x - BUILD_BLKS) * blockDim.x + threadIdx.x;
        if (p < n) {
            int k = bin_tile(pos[3 * p], pos[3 * p + 1], pos[3 * p + 2]);
            atomicAdd(&hist[k], 1u);
        }
        return;
    }

    __shared__ float sm[2][131][13];
    int bidx = blockIdx.x;              // 131 z * 66 y-pairs
    int yp = bidx % 66;
    int rz = 1 + bidx / 66;             // [1,131]
    int ry0 = 1 + 2 * yp;
    int t = threadIdx.x;

    for (int l = t; l < 262; l += 256) {
        int row = (l >= 131) ? 1 : 0;
        int cell = l - row * 131;
        int ry = ry0 + row;
        if (ry <= 131) {
            int xc = 1 + cell;
            uint32_t ux = (uint32_t)(xc - 2);
            uint32_t uy = (uint32_t)(ry - 2);
            uint32_t uz = (uint32_t)(rz - 2);
            uint32_t h = (ux ^ (uy * P2) ^ (uz * P3)) & TABLE_MASK;
            float4 g  = gauss[h];
            float4 v0 = vmf[(size_t)2 * h];
            float4 v1 = vmf[(size_t)2 * h + 1];
            float* s = sm[row][cell];
            s[0] = g.x;  s[1] = g.y;  s[2]  = g.z;  s[3]  = g.w;
            s[4] = v0.x; s[5] = v0.y; s[6]  = v0.z; s[7]  = v0.w;
            s[8] = v1.x; s[9] = v1.y; s[10] = v1.z; s[11] = v1.w;
        }
    }
    __syncthreads();

    int row = t >> 7;
    int c   = t & 127;
    int ry  = ry0 + row;
    if (ry > 131) return;

    uint32_t rec[12];
#pragma unroll
    for (int m = 0; m < 6; ++m) {
        float e0 = sm[row][c][2*m]   + sm[row][c+1][2*m]   + sm[row][c+2][2*m];
        float e1 = sm[row][c][2*m+1] + sm[row][c+1][2*m+1] + sm[row][c+2][2*m+1];
        float d0 = sm[row][c+3][2*m]   - sm[row][c][2*m];
        float d1 = sm[row][c+3][2*m+1] - sm[row][c][2*m+1];
        rec[m]     = f2h2(e0, e1);
        rec[6 + m] = f2h2(d0, d1);
    }
    size_t o = (((size_t)rz * YD + (size_t)ry) * XD + (size_t)c) * RECU;
    *(uint4*)(exdx + o)     = make_uint4(rec[0], rec[1], rec[2],  rec[3]);
    *(uint4*)(exdx + o + 4) = make_uint4(rec[4], rec[5], rec[6],  rec[7]);
    *(uint4*)(exdx + o + 8) = make_uint4(rec[8], rec[9], rec[10], rec[11]);
}

// ---------- single-block scan over 4096 bins: absolute exclusive prefix ----------
__global__ __launch_bounds__(1024)
void scan4k_kernel(const uint32_t* __restrict__ hist,
                   uint32_t* __restrict__ cursor,
                   uint32_t* __restrict__ binStart)
{
    __shared__ uint32_t buf[1024];
    __shared__ uint32_t running;
    int t = threadIdx.x;
    if (t == 0) running = 0u;
    __syncthreads();
    for (int base = 0; base < NBT; base += 1024) {
        uint32_t v = hist[base + t];
        buf[t] = v;
        __syncthreads();
        for (int off = 1; off < 1024; off <<= 1) {
            uint32_t x = (t >= off) ? buf[t - off] : 0u;
            __syncthreads();
            buf[t] += x;
            __syncthreads();
        }
        uint32_t incl = buf[t];
        uint32_t r0 = running;
        cursor[base + t]   = r0 + incl - v;
        binStart[base + t] = r0 + incl - v;
        __syncthreads();
        if (t == 1023) running = r0 + incl;
        __syncthreads();
    }
    if (t == 0) binStart[NBT] = running;
}

__global__ __launch_bounds__(256)
void scatter_kernel(const float* __restrict__ pos,
                    uint32_t* __restrict__ cursor,
                    float4* __restrict__ sortedPts, int n)
{
    int p = blockIdx.x * blockDim.x + threadIdx.x;
    if (p >= n) return;
    float px = pos[3 * p], py = pos[3 * p + 1], pz = pos[3 * p + 2];
    int k = bin_tile(px, py, pz);
    uint32_t slot = atomicAdd(&cursor[k], 1u);
    sortedPts[slot] = make_float4(px, py, pz, __uint_as_float((uint32_t)p));
}

// ---------- main: tile-staged LDS, SoA layout, conflict-free b32 reads ----------
__global__ __launch_bounds__(256)
void vapl_tile_kernel(const float4* __restrict__ sortedPts,
                      const uint32_t* __restrict__ exdx,
                      const uint32_t* __restrict__ binStart,
                      float* __restrict__ out,   // [N*4] then [N*7], f32
                      int n)
{
    __shared__ uint32_t lds[12][NREC];   // SoA: feature-uint m of record r at lds[m][r]

    int bid = blockIdx.x;
    int tile = ((bid & 7) << 9) | (bid >> 3);   // XCD-chunked, bijective (4096 % 8 == 0)
    int tx = tile & 15, ty = (tile >> 4) & 15, tz = tile >> 8;

    // ---- stage 968 records (coalesced 384 B rows) ----
    int x0  = tx * 8;
    int cy0 = ty * 8 + 1;
    int cz0 = tz * 8 + 1;
    for (int u4 = (int)threadIdx.x; u4 < NREC * 3; u4 += 256) {
        int rec = u4 / 3;
        int p   = u4 - rec * 3;
        int lx  = rec & 7;
        int t2  = rec >> 3;
        int ly  = t2 % 11;
        int lz  = t2 / 11;
        size_t goff = ((size_t)(cz0 + lz) * YD + (size_t)(cy0 + ly)) * XD + (size_t)(x0 + lx);
        uint4 v = *(const uint4*)(exdx + goff * RECU + (size_t)p * 4);
        int q = p * 4;
        lds[q + 0][rec] = v.x;
        lds[q + 1][rec] = v.y;
        lds[q + 2][rec] = v.z;
        lds[q + 3][rec] = v.w;
    }
    __syncthreads();

    int start = (int)binStart[tile];
    int end   = (int)binStart[tile + 1];

    for (int s = start + (int)threadIdx.x; s < end; s += 256) {
        float4 pt = sortedPts[s];
        int p = (int)__float_as_uint(pt.w);

        float x = ((pt.x + 10.0f) / 20.0f) * 128.0f;
        float y = ((pt.y + 10.0f) / 20.0f) * 128.0f;
        float z = ((pt.z + 10.0f) / 20.0f) * 128.0f;

        float fx = floorf(x), fy = floorf(y), fz = floorf(z);
        int ix = (int)fx, iy = (int)fy, iz = (int)fz;
        float wx = x - fx, wy = y - fy, wz = z - fz;

        float ay[4] = {1.0f - wy, 1.0f, 1.0f, wy};
        float az[4] = {1.0f - wz, 1.0f, 1.0f, wz};
        __half2 wxh = __float2half2_rn(wx);

        int r0 = (ix - x0) + 8 * ((iy - ty * 8) + 11 * (iz - tz * 8));

        float acc[12] = {0.f,0.f,0.f,0.f,0.f,0.f,0.f,0.f,0.f,0.f,0.f,0.f};
#pragma unroll
        for (int k = 0; k < 4; ++k) {
            float azk = az[k];
#pragma unroll
            for (int j = 0; j < 4; ++j) {
                int r = r0 + 8 * j + 88 * k;
                float w = ay[j] * azk;
#pragma unroll
                for (int m = 0; m < 6; ++m) {
                    __half2 v = __hfma2(wxh, u2h2(lds[6 + m][r]), u2h2(lds[m][r]));
                    float2 f = __half22float2(v);
                    acc[2*m]     = fmaf(w, f.x, acc[2*m]);
                    acc[2*m + 1] = fmaf(w, f.y, acc[2*m + 1]);
                }
            }
        }

        float m0 = sigmoidf_(acc[0]) * 20.0f - 10.0f;
        float m1 = sigmoidf_(acc[1]) * 20.0f - 10.0f;
        float m2 = sigmoidf_(acc[2]) * 20.0f - 10.0f;
        float var = fmaxf(acc[3], 0.0f) + log1pf(expf(-fabsf(acc[3])));

        float sharp = expf(acc[4]);
        float nrm = fmaxf(sqrtf(acc[5]*acc[5] + acc[6]*acc[6] + acc[7]*acc[7]), 1e-12f);
        float a0 = acc[5] / nrm, a1 = acc[6] / nrm, a2 = acc[7] / nrm;
        float amp0 = sigmoidf_(acc[8]);
        float amp1 = sigmoidf_(acc[9]);
        float amp2 = sigmoidf_(acc[10]);

        float* og = out + (size_t)p * 4;
        *(float4*)og = make_float4(m0, m1, m2, var);

        float* ov = out + (size_t)n * 4 + (size_t)p * 7;
        ov[0] = sharp;
        ov[1] = a0;
        ov[2] = a1;
        ov[3] = a2;
        ov[4] = amp0;
        ov[5] = amp1;
        ov[6] = amp2;
    }
}

// ---------- fallback (ws too small): round-2 two-table kernel ----------
__global__ __launch_bounds__(256)
void vapl_grid_kernel(const float* __restrict__ pos,
                      const float4* __restrict__ gauss,
                      const float4* __restrict__ vmf,
                      float* __restrict__ out,
                      int n)
{
    int p = blockIdx.x * blockDim.x + threadIdx.x;
    if (p >= n) return;

    float px = pos[3 * p + 0];
    float py = pos[3 * p + 1];
    float pz = pos[3 * p + 2];

    float x = ((px + 10.0f) / 20.0f) * 128.0f;
    float y = ((py + 10.0f) / 20.0f) * 128.0f;
    float z = ((pz + 10.0f) / 20.0f) * 128.0f;

    float fx = floorf(x), fy = floorf(y), fz = floorf(z);
    int ix = (int)fx, iy = (int)fy, iz = (int)fz;
    float wx = x - fx, wy = y - fy, wz = z - fz;

    float ax[4] = {1.0f - wx, 1.0f, 1.0f, wx};
    float ay[4] = {1.0f - wy, 1.0f, 1.0f, wy};
    float az[4] = {1.0f - wz, 1.0f, 1.0f, wz};

    uint32_t hx[4], hy[4], hz[4];
#pragma unroll
    for (int i = 0; i < 4; ++i) {
        hx[i] = (uint32_t)(ix - 1 + i);
        hy[i] = (uint32_t)(iy - 1 + i) * P2;
        hz[i] = (uint32_t)(iz - 1 + i) * P3;
    }

    float tg0 = 0.f, tg1 = 0.f, tg2 = 0.f, tg3 = 0.f;
    float tv0 = 0.f, tv1 = 0.f, tv2 = 0.f, tv3 = 0.f;
    float tv4 = 0.f, tv5 = 0.f, tv6 = 0.f, tv7 = 0.f;

    for (int k = 0; k < 4; ++k) {
        for (int j = 0; j < 4; ++j) {
            uint32_t hyz = hy[j] ^ hz[k];
            float wyz = ay[j] * az[k];
#pragma unroll
            for (int i = 0; i < 4; ++i) {
                uint32_t h = (hx[i] ^ hyz) & TABLE_MASK;
                float w = ax[i] * wyz;
                float4 g  = gauss[h];
                float4 v0 = vmf[(size_t)2 * h];
                float4 v1 = vmf[(size_t)2 * h + 1];
                tg0 = fmaf(w, g.x,  tg0);
                tg1 = fmaf(w, g.y,  tg1);
                tg2 = fmaf(w, g.z,  tg2);
                tg3 = fmaf(w, g.w,  tg3);
                tv0 = fmaf(w, v0.x, tv0);
                tv1 = fmaf(w, v0.y, tv1);
                tv2 = fmaf(w, v0.z, tv2);
                tv3 = fmaf(w, v0.w, tv3);
                tv4 = fmaf(w, v1.x, tv4);
                tv5 = fmaf(w, v1.y, tv5);
                tv6 = fmaf(w, v1.z, tv6);
                tv7 = fmaf(w, v1.w, tv7);
            }
        }
    }

    float m0 = sigmoidf_(tg0) * 20.0f - 10.0f;
    float m1 = sigmoidf_(tg1) * 20.0f - 10.0f;
    float m2 = sigmoidf_(tg2) * 20.0f - 10.0f;
    float var = fmaxf(tg3, 0.0f) + log1pf(expf(-fabsf(tg3)));

    float sharp = expf(tv0);
    float nrm = fmaxf(sqrtf(tv1 * tv1 + tv2 * tv2 + tv3 * tv3), 1e-12f);
    float a0 = tv1 / nrm, a1 = tv2 / nrm, a2 = tv3 / nrm;
    float amp0 = sigmoidf_(tv4);
    float amp1 = sigmoidf_(tv5);
    float amp2 = sigmoidf_(tv6);

    float* og = out + (size_t)p * 4;
    og[0] = m0;
    og[1] = m1;
    og[2] = m2;
    og[3] = var;

    float* ov = out + (size_t)n * 4 + (size_t)p * 7;
    ov[0] = sharp;
    ov[1] = a0;
    ov[2] = a1;
    ov[3] = a2;
    ov[4] = amp0;
    ov[5] = amp1;
    ov[6] = amp2;
}

extern "C" void kernel_launch(void* const* d_in, const int* in_sizes, int n_in,
                              void* d_out, int out_size, void* d_ws, size_t ws_size,
                              hipStream_t stream) {
    const float*  pos   = (const float*)d_in[0];
    const float4* gauss = (const float4*)d_in[1];
    const float4* vmf   = (const float4*)d_in[2];
    float* out = (float*)d_out;
    int n = in_sizes[0] / 3;   // 1048576

    // d_ws layout
    size_t off = 0;
    char* ws = (char*)d_ws;
    uint32_t* exdx     = (uint32_t*)(ws + off);  off += (size_t)XD * YD * ZD * RECU * 4;  // ~107 MB
    off = (off + 255) & ~(size_t)255;
    uint32_t* hist     = (uint32_t*)(ws + off);  off += (size_t)NBT * 4;
    uint32_t* cursor   = (uint32_t*)(ws + off);  off += (size_t)NBT * 4;
    uint32_t* binStart = (uint32_t*)(ws + off);  off += (size_t)(NBT + 1) * 4;
    off = (off + 255) & ~(size_t)255;
    float4* sortedPts  = (float4*)(ws + off);    off += (size_t)n * 16;                   // 16 MB
    const size_t need = off;

    dim3 block(256);
    dim3 grid((n + 255) / 256);

    if (ws_size >= need) {
        hipMemsetAsync(hist, 0, (size_t)NBT * 4, stream);
        hipLaunchKernelGGL(build_hist_kernel, dim3(BUILD_BLKS + 4096), block, 0, stream,
                           gauss, vmf, exdx, pos, hist, n);
        hipLaunchKernelGGL(scan4k_kernel, dim3(1), dim3(1024), 0, stream, hist, cursor, binStart);
        hipLaunchKernelGGL(scatter_kernel, grid, block, 0, stream, pos, cursor, sortedPts, n);
        hipLaunchKernelGGL(vapl_tile_kernel, dim3(NBT), block, 0, stream,
                           sortedPts, exdx, binStart, out, n);
    } else {
        hipLaunchKernelGGL(vapl_grid_kernel, grid, block, 0, stream, pos, gauss, vmf, out, n);
    }
}

// Round 12
// 309.411 us; speedup vs baseline: 1.0318x; 1.0318x over previous
//
#include <hip/hip_runtime.h>
#include <hip/hip_fp16.h>
#include <cstdint>

#define TABLE_MASK 0x3FFFFFu   // 2^22 - 1
#define P2 2654435761u
#define P3 805459861u

#define XD 128                  // exdx x-extent (record x = ix in [0,127])
#define YD 132                  // cy in [1,131]
#define ZD 132                  // cz in [1,131]
#define RECU 16                 // 16 uints = 64 B per cell: {Ex,Dx} interleaved + pad
#define NB3 (128 * 128 * 8)     // bins: (iz, iy, ix/16) raster = 131072
#define SCAN_BLKS (NB3 / 1024)  // 128
#define BUILD_BLKS (131 * 66)   // 8646

__device__ __forceinline__ float sigmoidf_(float x) { return 1.0f / (1.0f + expf(-x)); }

__device__ __forceinline__ uint32_t f2h2(float a, float b) {
    __half2 h = __floats2half2_rn(a, b);
    return *reinterpret_cast<uint32_t*>(&h);
}
__device__ __forceinline__ __half2 u2h2(uint32_t u) {
    return *reinterpret_cast<__half2*>(&u);
}

// ---------- sort key: raster (iz, iy, ix/16) ----------
__device__ __forceinline__ int bin_key3(float px, float py, float pz)
{
    float x = ((px + 10.0f) / 20.0f) * 128.0f;
    float y = ((py + 10.0f) / 20.0f) * 128.0f;
    float z = ((pz + 10.0f) / 20.0f) * 128.0f;
    int ix = min(max((int)floorf(x), 0), 127);
    int iy = min(max((int)floorf(y), 0), 127);
    int iz = min(max((int)floorf(z), 0), 127);
    return (((iz << 7) + iy) << 3) + (ix >> 4);
}

// ---------- fused prepass: build exdx volume (64 B records) + histogram ----------
__global__ __launch_bounds__(256)
void build_hist_kernel(const float4* __restrict__ gauss,
                       const float4* __restrict__ vmf,
                       uint32_t* __restrict__ exdx,
                       const float* __restrict__ pos,
                       uint32_t* __restrict__ hist, int n)
{
    if (blockIdx.x >= BUILD_BLKS) {
        int p = (blockIdx.x - BUILD_BLKS) * blockDim.x + threadIdx.x;
        if (p < n) {
            int k = bin_key3(pos[3 * p], pos[3 * p + 1], pos[3 * p + 2]);
            atomicAdd(&hist[k], 1u);
        }
        return;
    }

    __shared__ float sm[2][131][13];
    int bidx = blockIdx.x;              // 131 z * 66 y-pairs
    int yp = bidx % 66;
    int rz = 1 + bidx / 66;             // [1,131]
    int ry0 = 1 + 2 * yp;
    int t = threadIdx.x;

    for (int l = t; l < 262; l += 256) {
        int row = (l >= 131) ? 1 : 0;
        int cell = l - row * 131;
        int ry = ry0 + row;
        if (ry <= 131) {
            int xc = 1 + cell;
            uint32_t ux = (uint32_t)(xc - 2);
            uint32_t uy = (uint32_t)(ry - 2);
            uint32_t uz = (uint32_t)(rz - 2);
            uint32_t h = (ux ^ (uy * P2) ^ (uz * P3)) & TABLE_MASK;
            float4 g  = gauss[h];
            float4 v0 = vmf[(size_t)2 * h];
            float4 v1 = vmf[(size_t)2 * h + 1];
            float* s = sm[row][cell];
            s[0] = g.x;  s[1] = g.y;  s[2]  = g.z;  s[3]  = g.w;
            s[4] = v0.x; s[5] = v0.y; s[6]  = v0.z; s[7]  = v0.w;
            s[8] = v1.x; s[9] = v1.y; s[10] = v1.z; s[11] = v1.w;
        }
    }
    __syncthreads();

    int row = t >> 7;
    int c   = t & 127;
    int ry  = ry0 + row;
    if (ry > 131) return;

    uint32_t ex[6], dx[6];
#pragma unroll
    for (int m = 0; m < 6; ++m) {
        float e0 = sm[row][c][2*m]   + sm[row][c+1][2*m]   + sm[row][c+2][2*m];
        float e1 = sm[row][c][2*m+1] + sm[row][c+1][2*m+1] + sm[row][c+2][2*m+1];
        float d0 = sm[row][c+3][2*m]   - sm[row][c][2*m];
        float d1 = sm[row][c+3][2*m+1] - sm[row][c][2*m+1];
        ex[m] = f2h2(e0, e1);
        dx[m] = f2h2(d0, d1);
    }
    size_t o = (((size_t)rz * YD + (size_t)ry) * XD + (size_t)c) * RECU;
    *(uint4*)(exdx + o)      = make_uint4(ex[0], dx[0], ex[1], dx[1]);
    *(uint4*)(exdx + o + 4)  = make_uint4(ex[2], dx[2], ex[3], dx[3]);
    *(uint4*)(exdx + o + 8)  = make_uint4(ex[4], dx[4], ex[5], dx[5]);
    *(uint4*)(exdx + o + 12) = make_uint4(0u, 0u, 0u, 0u);
}

// ---------- scanA: per-1024-chunk exclusive prefix + chunk sums ----------
__global__ __launch_bounds__(1024)
void scanA_kernel(const uint32_t* __restrict__ hist,
                  uint32_t* __restrict__ cursor,
                  uint32_t* __restrict__ sums)
{
    __shared__ uint32_t buf[1024];
    int t = threadIdx.x;
    int base = blockIdx.x * 1024;
    uint32_t v = hist[base + t];
    buf[t] = v;
    __syncthreads();
    for (int off = 1; off < 1024; off <<= 1) {
        uint32_t x = (t >= off) ? buf[t - off] : 0u;
        __syncthreads();
        buf[t] += x;
        __syncthreads();
    }
    cursor[base + t] = buf[t] - v;
    if (t == 1023) sums[blockIdx.x] = buf[t];
}

// ---------- scatter: redundant in-block scan of 128 chunk sums, then place ----------
__global__ __launch_bounds__(256)
void scatter_kernel(const float* __restrict__ pos,
                    uint32_t* __restrict__ cursor,
                    const uint32_t* __restrict__ sums,
                    float4* __restrict__ sortedPts, int n)
{
    __shared__ uint32_t soff[SCAN_BLKS];
    int t = threadIdx.x;
    if (t < SCAN_BLKS) soff[t] = sums[t];
    __syncthreads();
    for (int off = 1; off < SCAN_BLKS; off <<= 1) {
        uint32_t v = 0;
        if (t < SCAN_BLKS && t >= off) v = soff[t - off];
        __syncthreads();
        if (t < SCAN_BLKS) soff[t] += v;
        __syncthreads();
    }

    int p = blockIdx.x * blockDim.x + t;
    if (p >= n) return;
    float px = pos[3 * p], py = pos[3 * p + 1], pz = pos[3 * p + 2];
    int k = bin_key3(px, py, pz);
    int chunk = k >> 10;
    uint32_t base = (chunk > 0) ? soff[chunk - 1] : 0u;
    uint32_t slot = base + atomicAdd(&cursor[k], 1u);
    sortedPts[slot] = make_float4(px, py, pz, __uint_as_float((uint32_t)p));
}

// ---------- main: 4 lanes per point; lane r loads uint4 r of each 64 B record ----------
__global__ __launch_bounds__(256, 2)
void vapl_group_kernel(const float4* __restrict__ sortedPts,
                       const uint32_t* __restrict__ exdx,
                       float* __restrict__ out,   // [N*4] then [N*7], f32
                       int n)
{
    int bid = blockIdx.x;
    int nb  = gridDim.x;
    int b2  = ((nb & 7) == 0) ? ((bid & 7) * (nb >> 3) + (bid >> 3)) : bid;
    int g   = b2 * 64 + ((int)threadIdx.x >> 2);   // point index (16 per wave)
    if (g >= n) return;
    int r = (int)threadIdx.x & 3;

    float4 pt = sortedPts[g];
    int p = (int)__float_as_uint(pt.w);

    float x = ((pt.x + 10.0f) / 20.0f) * 128.0f;
    float y = ((pt.y + 10.0f) / 20.0f) * 128.0f;
    float z = ((pt.z + 10.0f) / 20.0f) * 128.0f;

    float fx = floorf(x), fy = floorf(y), fz = floorf(z);
    int ix = (int)fx, iy = (int)fy, iz = (int)fz;
    float wx = x - fx, wy = y - fy, wz = z - fz;

    float ay[4] = {1.0f - wy, 1.0f, 1.0f, wy};
    float az[4] = {1.0f - wz, 1.0f, 1.0f, wz};
    __half2 wxh = __float2half2_rn(wx);

    int bx = ix + 1, by = iy + 1, bz = iz + 1;

    // load my uint4 of each of the 16 records (all 4 lanes share one 128B line)
    uint4 u[16];
#pragma unroll
    for (int k = 0; k < 4; ++k) {
#pragma unroll
        for (int j = 0; j < 4; ++j) {
            size_t cell = ((size_t)(bz + k) * YD + (size_t)(by + j)) * XD + (size_t)(bx - 1);
            u[k * 4 + j] = *(const uint4*)(exdx + cell * RECU + (size_t)(r * 4));
        }
    }

    // lane r accumulates features 4r..4r+3 (lane 3 accumulates padding)
    float a0 = 0.f, a1 = 0.f, a2 = 0.f, a3 = 0.f;
#pragma unroll
    for (int k = 0; k < 4; ++k) {
        float azk = az[k];
#pragma unroll
        for (int j = 0; j < 4; ++j) {
            float w = ay[j] * azk;
            uint4 v = u[k * 4 + j];
            __half2 t0 = __hfma2(wxh, u2h2(v.y), u2h2(v.x));   // Ex + wx*Dx (pair 0)
            __half2 t1 = __hfma2(wxh, u2h2(v.w), u2h2(v.z));   // pair 1
            float2 f0 = __half22float2(t0);
            float2 f1 = __half22float2(t1);
            a0 = fmaf(w, f0.x, a0);
            a1 = fmaf(w, f0.y, a1);
            a2 = fmaf(w, f1.x, a2);
            a3 = fmaf(w, f1.y, a3);
        }
    }

    if (r == 0) {
        // gauss features: mean + variance
        float m0 = sigmoidf_(a0) * 20.0f - 10.0f;
        float m1 = sigmoidf_(a1) * 20.0f - 10.0f;
        float m2 = sigmoidf_(a2) * 20.0f - 10.0f;
        float var = fmaxf(a3, 0.0f) + log1pf(expf(-fabsf(a3)));
        *(float4*)(out + (size_t)p * 4) = make_float4(m0, m1, m2, var);
    } else if (r == 1) {
        // vmf[0..3]: sharpness + axis
        float sharp = expf(a0);
        float nrm = fmaxf(sqrtf(a1 * a1 + a2 * a2 + a3 * a3), 1e-12f);
        float* ov = out + (size_t)n * 4 + (size_t)p * 7;
        ov[0] = sharp;
        ov[1] = a1 / nrm;
        ov[2] = a2 / nrm;
        ov[3] = a3 / nrm;
    } else if (r == 2) {
        // vmf[4..6]: amplitude
        float* ov = out + (size_t)n * 4 + (size_t)p * 7;
        ov[4] = sigmoidf_(a0);
        ov[5] = sigmoidf_(a1);
        ov[6] = sigmoidf_(a2);
    }
}

// ---------- fallback (ws too small): round-2 two-table kernel ----------
__global__ __launch_bounds__(256)
void vapl_grid_kernel(const float* __restrict__ pos,
                      const float4* __restrict__ gauss,
                      const float4* __restrict__ vmf,
                      float* __restrict__ out,
                      int n)
{
    int p = blockIdx.x * blockDim.x + threadIdx.x;
    if (p >= n) return;

    float px = pos[3 * p + 0];
    float py = pos[3 * p + 1];
    float pz = pos[3 * p + 2];

    float x = ((px + 10.0f) / 20.0f) * 128.0f;
    float y = ((py + 10.0f) / 20.0f) * 128.0f;
    float z = ((pz + 10.0f) / 20.0f) * 128.0f;

    float fx = floorf(x), fy = floorf(y), fz = floorf(z);
    int ix = (int)fx, iy = (int)fy, iz = (int)fz;
    float wx = x - fx, wy = y - fy, wz = z - fz;

    float ax[4] = {1.0f - wx, 1.0f, 1.0f, wx};
    float ay[4] = {1.0f - wy, 1.0f, 1.0f, wy};
    float az[4] = {1.0f - wz, 1.0f, 1.0f, wz};

    uint32_t hx[4], hy[4], hz[4];
#pragma unroll
    for (int i = 0; i < 4; ++i) {
        hx[i] = (uint32_t)(ix - 1 + i);
        hy[i] = (uint32_t)(iy - 1 + i) * P2;
        hz[i] = (uint32_t)(iz - 1 + i) * P3;
    }

    float tg0 = 0.f, tg1 = 0.f, tg2 = 0.f, tg3 = 0.f;
    float tv0 = 0.f, tv1 = 0.f, tv2 = 0.f, tv3 = 0.f;
    float tv4 = 0.f, tv5 = 0.f, tv6 = 0.f, tv7 = 0.f;

    for (int k = 0; k < 4; ++k) {
        for (int j = 0; j < 4; ++j) {
            uint32_t hyz = hy[j] ^ hz[k];
            float wyz = ay[j] * az[k];
#pragma unroll
            for (int i = 0; i < 4; ++i) {
                uint32_t h = (hx[i] ^ hyz) & TABLE_MASK;
                float w = ax[i] * wyz;
                float4 g  = gauss[h];
                float4 v0 = vmf[(size_t)2 * h];
                float4 v1 = vmf[(size_t)2 * h + 1];
                tg0 = fmaf(w, g.x,  tg0);
                tg1 = fmaf(w, g.y,  tg1);
                tg2 = fmaf(w, g.z,  tg2);
                tg3 = fmaf(w, g.w,  tg3);
                tv0 = fmaf(w, v0.x, tv0);
                tv1 = fmaf(w, v0.y, tv1);
                tv2 = fmaf(w, v0.z, tv2);
                tv3 = fmaf(w, v0.w, tv3);
                tv4 = fmaf(w, v1.x, tv4);
                tv5 = fmaf(w, v1.y, tv5);
                tv6 = fmaf(w, v1.z, tv6);
                tv7 = fmaf(w, v1.w, tv7);
            }
        }
    }

    float m0 = sigmoidf_(tg0) * 20.0f - 10.0f;
    float m1 = sigmoidf_(tg1) * 20.0f - 10.0f;
    float m2 = sigmoidf_(tg2) * 20.0f - 10.0f;
    float var = fmaxf(tg3, 0.0f) + log1pf(expf(-fabsf(tg3)));

    float sharp = expf(tv0);
    float nrm = fmaxf(sqrtf(tv1 * tv1 + tv2 * tv2 + tv3 * tv3), 1e-12f);
    float a0 = tv1 / nrm, a1 = tv2 / nrm, a2 = tv3 / nrm;
    float amp0 = sigmoidf_(tv4);
    float amp1 = sigmoidf_(tv5);
    float amp2 = sigmoidf_(tv6);

    float* og = out + (size_t)p * 4;
    og[0] = m0;
    og[1] = m1;
    og[2] = m2;
    og[3] = var;

    float* ov = out + (size_t)n * 4 + (size_t)p * 7;
    ov[0] = sharp;
    ov[1] = a0;
    ov[2] = a1;
    ov[3] = a2;
    ov[4] = amp0;
    ov[5] = amp1;
    ov[6] = amp2;
}

extern "C" void kernel_launch(void* const* d_in, const int* in_sizes, int n_in,
                              void* d_out, int out_size, void* d_ws, size_t ws_size,
                              hipStream_t stream) {
    const float*  pos   = (const float*)d_in[0];
    const float4* gauss = (const float4*)d_in[1];
    const float4* vmf   = (const float4*)d_in[2];
    float* out = (float*)d_out;
    int n = in_sizes[0] / 3;   // 1048576

    // d_ws layout
    size_t off = 0;
    char* ws = (char*)d_ws;
    uint32_t* exdx   = (uint32_t*)(ws + off);  off += (size_t)XD * YD * ZD * RECU * 4;  // ~143 MB
    off = (off + 255) & ~(size_t)255;
    uint32_t* hist   = (uint32_t*)(ws + off);  off += (size_t)NB3 * 4;
    uint32_t* cursor = (uint32_t*)(ws + off);  off += (size_t)NB3 * 4;
    uint32_t* sums   = (uint32_t*)(ws + off);  off += 256 * 4;
    off = (off + 255) & ~(size_t)255;
    float4* sortedPts = (float4*)(ws + off);   off += (size_t)n * 16;                   // 16 MB
    const size_t need = off;

    dim3 block(256);
    dim3 grid((n + 255) / 256);

    if (ws_size >= need) {
        hipMemsetAsync(hist, 0, (size_t)NB3 * 4, stream);
        hipLaunchKernelGGL(build_hist_kernel, dim3(BUILD_BLKS + 4096), block, 0, stream,
                           gauss, vmf, exdx, pos, hist, n);
        hipLaunchKernelGGL(scanA_kernel, dim3(SCAN_BLKS), dim3(1024), 0, stream, hist, cursor, sums);
        hipLaunchKernelGGL(scatter_kernel, grid, block, 0, stream, pos, cursor, sums, sortedPts, n);
        // 4 lanes per point -> 64 points per 256-thread block
        dim3 ggrid((unsigned)((n + 63) / 64));
        hipLaunchKernelGGL(vapl_group_kernel, ggrid, block, 0, stream,
                           sortedPts, exdx, out, n);
    } else {
        hipLaunchKernelGGL(vapl_grid_kernel, grid, block, 0, stream, pos, gauss, vmf, out, n);
    }
}